// Round 8
// baseline (197.682 us; speedup 1.0000x reference)
//
#include <hip/hip_runtime.h>
#include <hip/hip_bf16.h>
#include <cstdint>
#include <cstddef>

// Problem constants
constexpr int T_TOK = 4096;   // B*S
constexpr int H_DIM = 1024;
constexpr int E_NUM = 8;
constexpr int I_DIM = 1024;
constexpr int F2    = 2048;   // 2*I
constexpr float ALPHA = 1.702f;
constexpr float LIMIT = 7.0f;
constexpr int BK  = 64;       // K tile (8 octets/row, 128B LDS rows)
constexpr int NKT = 16;       // K / BK
constexpr int MAXT1 = 72;     // gemm1 tiles (BM=128): sum ceil(cnt/128) <= 71
constexpr int MAXT2 = 40;     // gemm2 tiles (BM=256): sum ceil(cnt/256) <= 39

using u16    = unsigned short;
using bf16x8 = __attribute__((ext_vector_type(8))) __bf16;
using s16x8  = __attribute__((ext_vector_type(8))) short;
using f32x4  = __attribute__((ext_vector_type(4))) float;

// Workspace layout (bytes). DOWN aliases W1T (gemm1 finishes with W1T before
// gemm2 writes DOWN; transposes rewrite W1T every call — deterministic).
constexpr size_t WS_W1T  = 0;                        // [E][2][I][H] bf16
constexpr size_t WS_DOWN = 0;                        // [8192][H] bf16 (alias)
constexpr size_t WS_W2T  = 33554432;                 // [E][H][I] bf16
constexpr size_t WS_ACT  = 50331648;                 // [8192][I] bf16
constexpr size_t WS_ETOK = 67108864;                 // [E][T] int
constexpr size_t WS_POS  = 67239936;                 // [T] int2
constexpr size_t WS_CNT  = 67272704;                 // [E] int
constexpr size_t WS_ROWB = 67272736;                 // [E] int
constexpr size_t WS_ASG1 = 67272768;                 // [MAXT1] int
constexpr size_t WS_ASG2 = 67272768 + 512;           // [MAXT2] int
constexpr size_t WS_TOPE = 67273792;                 // [T] int
constexpr size_t WS_TOPW = 67290176;                 // [T] float2
constexpr size_t WS_XBF  = 67322944;                 // [T][H] bf16
constexpr size_t WS_NEED = 75711552;

__device__ __forceinline__ u16 f2bf(float f) {
    union { float f; unsigned u; } v; v.f = f;
    return (u16)((v.u + 0x7FFFu + ((v.u >> 16) & 1u)) >> 16);   // RNE
}
__device__ __forceinline__ float bf2f(u16 u) {
    union { unsigned u; float f; } v; v.u = (unsigned)u << 16; return v.f;
}

__device__ __forceinline__ s16x8 pack8(float4 a, float4 b) {
    s16x8 r;
    r[0] = (short)f2bf(a.x); r[1] = (short)f2bf(a.y);
    r[2] = (short)f2bf(a.z); r[3] = (short)f2bf(a.w);
    r[4] = (short)f2bf(b.x); r[5] = (short)f2bf(b.y);
    r[6] = (short)f2bf(b.z); r[7] = (short)f2bf(b.w);
    return r;
}

// async global -> LDS, 16B per lane. LDS dest = wave-uniform base + lane*16.
__device__ __forceinline__ void gload16(const void* g, void* l) {
    __builtin_amdgcn_global_load_lds((const __attribute__((address_space(1))) unsigned*)g,
                                     (__attribute__((address_space(3))) unsigned*)l,
                                     16, 0, 0);
}

#define BAR() __builtin_amdgcn_s_barrier()
#define WVM(n) asm volatile("s_waitcnt vmcnt(" #n ")" ::: "memory")

// ---------------------------------------------------------------------------
// x fp32 -> bf16 (once)
// ---------------------------------------------------------------------------
__global__ __launch_bounds__(256) void k_xbf(const float* __restrict__ x,
                                             u16* __restrict__ xbf) {
    const size_t i = ((size_t)blockIdx.x * 256 + threadIdx.x) * 8;
    float4 a = *(const float4*)(x + i);
    float4 b = *(const float4*)(x + i + 4);
    *(s16x8*)(xbf + i) = pack8(a, b);
}

// ---------------------------------------------------------------------------
// Transpose gate_up_proj [E][H][2I] fp32 -> [E][2][I][H] bf16 (de-interleave)
// ---------------------------------------------------------------------------
__global__ __launch_bounds__(256) void k_transpose_w1(const float* __restrict__ in,
                                                      u16* __restrict__ out) {
    __shared__ float tile[64][65];
    const int e = blockIdx.z, c0 = blockIdx.x * 64, h0 = blockIdx.y * 64;
    const int tid = threadIdx.x;
    const float* src = in + ((size_t)e * H_DIM + h0) * F2 + c0;
#pragma unroll
    for (int i = 0; i < 4; ++i) {
        int r = (tid >> 4) + i * 16, c = (tid & 15) * 4;
        float4 v = *(const float4*)(src + (size_t)r * F2 + c);
        tile[r][c] = v.x; tile[r][c + 1] = v.y; tile[r][c + 2] = v.z; tile[r][c + 3] = v.w;
    }
    __syncthreads();
    const int c = tid >> 2, hseg = (tid & 3) * 16;
    const int g = c & 1;
    const int f = (c0 + c) >> 1;
    u16* dst = out + (((size_t)e * 2 + g) * I_DIM + f) * H_DIM + h0 + hseg;
    s16x8 o0, o1;
#pragma unroll
    for (int j = 0; j < 8; ++j) o0[j] = (short)f2bf(tile[hseg + j][c]);
#pragma unroll
    for (int j = 0; j < 8; ++j) o1[j] = (short)f2bf(tile[hseg + 8 + j][c]);
    *(s16x8*)dst = o0;
    *(s16x8*)(dst + 8) = o1;
}

// ---------------------------------------------------------------------------
// Transpose down_proj [E][I][H] fp32 -> [E][H][I] bf16
// ---------------------------------------------------------------------------
__global__ __launch_bounds__(256) void k_transpose_w2(const float* __restrict__ in,
                                                      u16* __restrict__ out) {
    __shared__ float tile[64][65];
    const int e = blockIdx.z, h0 = blockIdx.x * 64, i0 = blockIdx.y * 64;
    const int tid = threadIdx.x;
    const float* src = in + ((size_t)e * I_DIM + i0) * H_DIM + h0;
#pragma unroll
    for (int i = 0; i < 4; ++i) {
        int r = (tid >> 4) + i * 16, c = (tid & 15) * 4;
        float4 v = *(const float4*)(src + (size_t)r * H_DIM + c);
        tile[r][c] = v.x; tile[r][c + 1] = v.y; tile[r][c + 2] = v.z; tile[r][c + 3] = v.w;
    }
    __syncthreads();
    const int c = tid >> 2, iseg = (tid & 3) * 16;
    u16* dst = out + ((size_t)e * H_DIM + h0 + c) * I_DIM + i0 + iseg;
    s16x8 o0, o1;
#pragma unroll
    for (int j = 0; j < 8; ++j) o0[j] = (short)f2bf(tile[iseg + j][c]);
#pragma unroll
    for (int j = 0; j < 8; ++j) o1[j] = (short)f2bf(tile[iseg + 8 + j][c]);
    *(s16x8*)dst = o0;
    *(s16x8*)(dst + 8) = o1;
}

// ---------------------------------------------------------------------------
// Router phase 1: fp32 logits, top-2, softmax. One wave per token. No atomics.
// ---------------------------------------------------------------------------
__global__ __launch_bounds__(256) void k_router_top2(const float* __restrict__ x,
                                                     const float* __restrict__ rw,
                                                     int* __restrict__ tope,
                                                     float2* __restrict__ topw) {
    const int wave = threadIdx.x >> 6, lane = threadIdx.x & 63;
    const int t = blockIdx.x * 4 + wave;
    const float* xr = x + (size_t)t * H_DIM;
    float acc[E_NUM];
#pragma unroll
    for (int e = 0; e < E_NUM; ++e) acc[e] = 0.f;
    for (int h = lane; h < H_DIM; h += 64) {
        float xv = xr[h];
        const float* r = rw + h * E_NUM;
#pragma unroll
        for (int e = 0; e < E_NUM; ++e) acc[e] += xv * r[e];
    }
#pragma unroll
    for (int e = 0; e < E_NUM; ++e) {
        float v = acc[e];
#pragma unroll
        for (int o = 32; o > 0; o >>= 1) v += __shfl_down(v, o);
        acc[e] = v;
    }
    if (lane == 0) {
        int e0 = 0; float v0 = acc[0];
#pragma unroll
        for (int e = 1; e < E_NUM; ++e) if (acc[e] > v0) { v0 = acc[e]; e0 = e; }
        int e1 = -1; float v1 = -3.4e38f;
#pragma unroll
        for (int e = 0; e < E_NUM; ++e) if (e != e0 && acc[e] > v1) { v1 = acc[e]; e1 = e; }
        float ew = expf(v1 - v0);
        float inv = 1.f / (1.f + ew);
        tope[t] = e0 | (e1 << 8);
        topw[t] = make_float2(inv, ew * inv);
    }
}

// ---------------------------------------------------------------------------
// Router phase 2: block-aggregated scatter (1 global atomic per expert/block).
// ---------------------------------------------------------------------------
__global__ __launch_bounds__(256) void k_router_scatter(const int* __restrict__ tope,
                                                        int* __restrict__ cnt,
                                                        int* __restrict__ ent_tok,
                                                        int2* __restrict__ pos) {
    __shared__ int lcnt[E_NUM];
    __shared__ int gbase[E_NUM];
    const int tid = threadIdx.x;
    const int t = blockIdx.x * 256 + tid;
    if (tid < E_NUM) lcnt[tid] = 0;
    __syncthreads();
    const int pk = tope[t];
    const int e0 = pk & 0xff, e1 = pk >> 8;
    const int o0 = atomicAdd(&lcnt[e0], 1);
    const int o1 = atomicAdd(&lcnt[e1], 1);
    __syncthreads();
    if (tid < E_NUM) gbase[tid] = atomicAdd(&cnt[tid], lcnt[tid]);
    __syncthreads();
    const int p0 = gbase[e0] + o0;
    const int p1 = gbase[e1] + o1;
    ent_tok[e0 * T_TOK + p0] = t;
    ent_tok[e1 * T_TOK + p1] = t;
    pos[t] = make_int2(p0, p1);
}

// ---------------------------------------------------------------------------
// Schedule: counts -> row bases + two tile tables (BM=128 and BM=256).
// ---------------------------------------------------------------------------
__global__ void k_schedule(const int* __restrict__ cnt, int* __restrict__ rowbase,
                           int* __restrict__ a1, int* __restrict__ a2) {
    if (threadIdx.x == 0) {
        int rb = 0, n1 = 0, n2 = 0;
        for (int e = 0; e < E_NUM; ++e) {
            rowbase[e] = rb;
            int t1 = (cnt[e] + 127) >> 7;
            for (int m = 0; m < t1; ++m) a1[n1++] = (e << 16) | m;
            int t2 = (cnt[e] + 255) >> 8;
            for (int m = 0; m < t2; ++m) a2[n2++] = (e << 16) | m;
            rb += cnt[e];
        }
        for (; n1 < MAXT1; ++n1) a1[n1] = -1;
        for (; n2 < MAXT2; ++n2) a2[n2] = -1;
    }
}

// ===========================================================================
// GEMM1 — phase-interleaved counted-vmcnt schedule (T3+T4).
// BM=128 rows x 256 B-rows (=128 act-cols, gate/up interleaved by 16), BK=64.
// 512 thr / 8 waves. Per K-tile: 4 phases, each = one C-quadrant (mh,nh):
//   { stage 1 half-tile of kt+1 ; counted vmcnt ; barrier ;
//     ds_read quadrant frags ; setprio(1) 8xMFMA setprio(0) ; barrier }
// Stage order per kt: [A-h0(1), B-h0(2), B-h1(2), A-h1(1)] (6 loads/thread).
// Waits (derived by in-flight accounting): p0 WVM(4), p1 WVM(4), p2 WVM(5),
// p3 none; last kt: 3/1/0. LDS 96KB (A 32KB + B 64KB), XOR-8 swizzle.
// ===========================================================================
__global__ __launch_bounds__(512, 2) void k_gemm1(
    const u16* __restrict__ xbf, const u16* __restrict__ w1t,
    const float* __restrict__ bias, const int* __restrict__ ent_tok,
    const int* __restrict__ cnt, const int* __restrict__ rowbase,
    const int* __restrict__ assign, u16* __restrict__ act) {
    const int a = assign[blockIdx.y];
    if (a < 0) return;
    const int e = a >> 16, mt = a & 0xffff;
    const int j0 = blockIdx.x * 128;                 // act-col base
    const int cs = cnt[e], r0 = mt * 128, rbase = rowbase[e];
    __shared__ __align__(16) u16 As[2 * 2 * 64 * 64];    // [d][half(64r)][r][k] 32KB
    __shared__ __align__(16) u16 Bs[2 * 2 * 128 * 64];   // [d][half(128r)][r][k] 64KB
    const int tid = threadIdx.x, lane = tid & 63, wv = tid >> 6;
    const int lcol = lane & 15, lk = lane >> 4;
    const int lr8 = lane >> 3;
    const int sg  = (lane & 7) ^ (lr8 & 7);          // inverse-swizzled src octet

    // ---- staging sources (per-thread, k-offset added per kt) ----
    const int arow0 = 0 * 64 + wv * 8 + lr8;         // A half 0
    const int arow1 = 1 * 64 + wv * 8 + lr8;         // A half 1
    const int ae0 = r0 + arow0, ae1 = r0 + arow1;
    const int tok0 = (ae0 < cs) ? ent_tok[e * T_TOK + ae0] : 0;
    const int tok1 = (ae1 < cs) ? ent_tok[e * T_TOK + ae1] : 0;
    const u16* aS0 = xbf + (size_t)tok0 * H_DIM + sg * 8;
    const u16* aS1 = xbf + (size_t)tok1 * H_DIM + sg * 8;
    // B rows: brow = h*128 + i*64 + wv*8 + lr8; pair=brow>>4, gu=pair&1,
    // acol = j0 + (pair>>1)*16 + (brow&15)
    const u16* bS[2][2];
#pragma unroll
    for (int h = 0; h < 2; ++h)
#pragma unroll
        for (int i = 0; i < 2; ++i) {
            const int brow = h * 128 + i * 64 + wv * 8 + lr8;
            const int pair = brow >> 4, gu = pair & 1;
            const int acol = j0 + (pair >> 1) * 16 + (brow & 15);
            bS[h][i] = w1t + (((size_t)e * 2 + gu) * I_DIM + acol) * H_DIM + sg * 8;
        }

    // ---- compute-side byte offsets ----
    int swz[2];
#pragma unroll
    for (int kk = 0; kk < 2; ++kk) swz[kk] = (((kk * 4 + lk) ^ (lcol & 7)) << 4);
    int aro[2], bro[2];
#pragma unroll
    for (int mi = 0; mi < 2; ++mi) aro[mi] = ((wv & 1) * 32 + mi * 16 + lcol) * 128;
#pragma unroll
    for (int nj = 0; nj < 2; ++nj) bro[nj] = ((wv >> 1) * 32 + nj * 16 + lcol) * 128;
    const char* AbC = (const char*)As;
    const char* BbC = (const char*)Bs;

    f32x4 acc[2][2][2][2];   // [mh][mi][nh][nj]  (nj: 0=gate, 1=up)
    const f32x4 z = {0.f, 0.f, 0.f, 0.f};
#pragma unroll
    for (int mh = 0; mh < 2; ++mh)
#pragma unroll
        for (int mi = 0; mi < 2; ++mi)
#pragma unroll
            for (int nh = 0; nh < 2; ++nh)
#pragma unroll
                for (int nj = 0; nj < 2; ++nj) acc[mh][mi][nh][nj] = z;

    // ---- prologue: stage kt0 into d=0 fully, drain ----
    gload16(aS0, (u16*)As + 0 * 4096 + wv * 512);
    gload16(aS1, (u16*)As + 1 * 4096 + wv * 512);
    gload16(bS[0][0], (u16*)Bs + 0 * 8192 + 0 * 4096 + wv * 512);
    gload16(bS[0][1], (u16*)Bs + 0 * 8192 + 1 * 4096 + wv * 512);
    gload16(bS[1][0], (u16*)Bs + 1 * 8192 + 0 * 4096 + wv * 512);
    gload16(bS[1][1], (u16*)Bs + 1 * 8192 + 1 * 4096 + wv * 512);
    WVM(0);
    BAR();

    bf16x8 aF[2][2], bF0[2][2], bF1[2][2];

    for (int kt = 0; kt < NKT; ++kt) {
        const int d = kt & 1, d2 = d ^ 1;
        const int dA = d * 16384, dB = d * 32768;    // byte bases of cur buffers
        const int kno = (kt + 1) * BK;
        const bool st = (kt + 1 < NKT);

        // ---------------- phase 0: quadrant (mh=0, nh=0) ----------------
        if (st) { gload16(aS0 + kno, (u16*)As + (d2 * 2 + 0) * 4096 + wv * 512); WVM(4); }
        else    { WVM(3); }
        BAR();
#pragma unroll
        for (int mi = 0; mi < 2; ++mi)
#pragma unroll
            for (int kk = 0; kk < 2; ++kk)
                aF[mi][kk] = *(const bf16x8*)(AbC + dA + 0 * 8192 + aro[mi] + swz[kk]);
#pragma unroll
        for (int nj = 0; nj < 2; ++nj)
#pragma unroll
            for (int kk = 0; kk < 2; ++kk)
                bF0[nj][kk] = *(const bf16x8*)(BbC + dB + 0 * 16384 + bro[nj] + swz[kk]);
        __builtin_amdgcn_s_setprio(1);
#pragma unroll
        for (int mi = 0; mi < 2; ++mi)
#pragma unroll
            for (int nj = 0; nj < 2; ++nj)
#pragma unroll
                for (int kk = 0; kk < 2; ++kk)
                    acc[0][mi][0][nj] = __builtin_amdgcn_mfma_f32_16x16x32_bf16(aF[mi][kk], bF0[nj][kk], acc[0][mi][0][nj], 0, 0, 0);
        __builtin_amdgcn_s_setprio(0);
        BAR();

        // ---------------- phase 1: quadrant (mh=0, nh=1) ----------------
        if (st) {
            gload16(bS[0][0] + kno, (u16*)Bs + (d2 * 2 + 0) * 8192 + 0 * 4096 + wv * 512);
            gload16(bS[0][1] + kno, (u16*)Bs + (d2 * 2 + 0) * 8192 + 1 * 4096 + wv * 512);
            WVM(4);
        } else { WVM(1); }
        BAR();
#pragma unroll
        for (int nj = 0; nj < 2; ++nj)
#pragma unroll
            for (int kk = 0; kk < 2; ++kk)
                bF1[nj][kk] = *(const bf16x8*)(BbC + dB + 1 * 16384 + bro[nj] + swz[kk]);
        __builtin_amdgcn_s_setprio(1);
#pragma unroll
        for (int mi = 0; mi < 2; ++mi)
#pragma unroll
            for (int nj = 0; nj < 2; ++nj)
#pragma unroll
                for (int kk = 0; kk < 2; ++kk)
                    acc[0][mi][1][nj] = __builtin_amdgcn_mfma_f32_16x16x32_bf16(aF[mi][kk], bF1[nj][kk], acc[0][mi][1][nj], 0, 0, 0);
        __builtin_amdgcn_s_setprio(0);
        BAR();

        // ---------------- phase 2: quadrant (mh=1, nh=0) ----------------
        if (st) {
            gload16(bS[1][0] + kno, (u16*)Bs + (d2 * 2 + 1) * 8192 + 0 * 4096 + wv * 512);
            gload16(bS[1][1] + kno, (u16*)Bs + (d2 * 2 + 1) * 8192 + 1 * 4096 + wv * 512);
            WVM(5);
        } else { WVM(0); }
        BAR();
#pragma unroll
        for (int mi = 0; mi < 2; ++mi)
#pragma unroll
            for (int kk = 0; kk < 2; ++kk)
                aF[mi][kk] = *(const bf16x8*)(AbC + dA + 1 * 8192 + aro[mi] + swz[kk]);
        __builtin_amdgcn_s_setprio(1);
#pragma unroll
        for (int mi = 0; mi < 2; ++mi)
#pragma unroll
            for (int nj = 0; nj < 2; ++nj)
#pragma unroll
                for (int kk = 0; kk < 2; ++kk)
                    acc[1][mi][0][nj] = __builtin_amdgcn_mfma_f32_16x16x32_bf16(aF[mi][kk], bF0[nj][kk], acc[1][mi][0][nj], 0, 0, 0);
        __builtin_amdgcn_s_setprio(0);
        BAR();

        // ---------------- phase 3: quadrant (mh=1, nh=1) ----------------
        if (st) gload16(aS1 + kno, (u16*)As + (d2 * 2 + 1) * 4096 + wv * 512);
        BAR();
        __builtin_amdgcn_s_setprio(1);
#pragma unroll
        for (int mi = 0; mi < 2; ++mi)
#pragma unroll
            for (int nj = 0; nj < 2; ++nj)
#pragma unroll
                for (int kk = 0; kk < 2; ++kk)
                    acc[1][mi][1][nj] = __builtin_amdgcn_mfma_f32_16x16x32_bf16(aF[mi][kk], bF1[nj][kk], acc[1][mi][1][nj], 0, 0, 0);
        __builtin_amdgcn_s_setprio(0);
        BAR();
    }

    // ---- epilogue: clamp + GLU (gate/up are nj=0/1 of same act-col) ----
#pragma unroll
    for (int mh = 0; mh < 2; ++mh)
#pragma unroll
        for (int mi = 0; mi < 2; ++mi)
#pragma unroll
            for (int nh = 0; nh < 2; ++nh) {
                const int acol = j0 + (nh * 4 + (wv >> 1)) * 16 + lcol;
                const float bg_ = bias[e * F2 + 2 * acol];
                const float bu_ = bias[e * F2 + 2 * acol + 1];
#pragma unroll
                for (int rg = 0; rg < 4; ++rg) {
                    const int row = mh * 64 + (wv & 1) * 32 + mi * 16 + lk * 4 + rg;
                    if (r0 + row < cs) {
                        float gv = acc[mh][mi][nh][0][rg] + bg_;
                        float uv = acc[mh][mi][nh][1][rg] + bu_;
                        gv = fminf(gv, LIMIT);
                        uv = fminf(fmaxf(uv, -LIMIT), LIMIT);
                        const float glu = gv / (1.f + expf(-ALPHA * gv));
                        act[(size_t)(rbase + r0 + row) * I_DIM + acol] = f2bf((uv + 1.f) * glu);
                    }
                }
            }
}

// ===========================================================================
// GEMM2 — same schedule. BM=256 rows x 128 out-cols, BK=64.
// A halves = 128 rows (2 loads), B halves = 64 rows (1 load).
// Stage order per kt: [A-h0(2), B-h0(1), B-h1(1), A-h1(2)].
// Waits: p0 WVM(5), p1 WVM(5), p2 WVM(4), p3 none; last kt: 3/2/0.
// LDS 96KB (A 64KB + B 32KB). Writes raw DOWN bf16 (combine applies w+bias).
// ===========================================================================
__global__ __launch_bounds__(512, 2) void k_gemm2(
    const u16* __restrict__ actb, const u16* __restrict__ w2t,
    const int* __restrict__ cnt, const int* __restrict__ rowbase,
    const int* __restrict__ assign, u16* __restrict__ down) {
    const int a = assign[blockIdx.y];
    if (a < 0) return;
    const int e = a >> 16, mt = a & 0xffff;
    const int n0 = blockIdx.x * 128;
    const int cs = cnt[e], r0 = mt * 256, rbase = rowbase[e];
    __shared__ __align__(16) u16 As[2 * 2 * 128 * 64];   // 64KB
    __shared__ __align__(16) u16 Bs[2 * 2 * 64 * 64];    // 32KB
    const int tid = threadIdx.x, lane = tid & 63, wv = tid >> 6;
    const int lcol = lane & 15, lk = lane >> 4;
    const int lr8 = lane >> 3;
    const int sg  = (lane & 7) ^ (lr8 & 7);

    // A sources: rows h*128 + i*64 + wv*8 + lr8 (contiguous grouped act rows)
    const u16* aS[2][2];
#pragma unroll
    for (int h = 0; h < 2; ++h)
#pragma unroll
        for (int i = 0; i < 2; ++i) {
            const int row = h * 128 + i * 64 + wv * 8 + lr8;
            int ar = rbase + r0 + row;
            if (ar > 2 * T_TOK - 1) ar = 2 * T_TOK - 1;
            aS[h][i] = actb + (size_t)ar * I_DIM + sg * 8;
        }
    // B sources: half h rows h*64 + wv*8 + lr8 -> col n0+brow
    const u16* bS[2];
#pragma unroll
    for (int h = 0; h < 2; ++h) {
        const int brow = h * 64 + wv * 8 + lr8;
        bS[h] = w2t + ((size_t)e * H_DIM + n0 + brow) * I_DIM + sg * 8;
    }

    int swz[2];
#pragma unroll
    for (int kk = 0; kk < 2; ++kk) swz[kk] = (((kk * 4 + lk) ^ (lcol & 7)) << 4);
    int aro[2], bro[2];
#pragma unroll
    for (int mi = 0; mi < 2; ++mi) aro[mi] = ((wv & 3) * 32 + mi * 16 + lcol) * 128;
#pragma unroll
    for (int nj = 0; nj < 2; ++nj) bro[nj] = ((wv >> 2) * 32 + nj * 16 + lcol) * 128;
    const char* AbC = (const char*)As;
    const char* BbC = (const char*)Bs;

    f32x4 acc[2][2][2][2];
    const f32x4 z = {0.f, 0.f, 0.f, 0.f};
#pragma unroll
    for (int mh = 0; mh < 2; ++mh)
#pragma unroll
        for (int mi = 0; mi < 2; ++mi)
#pragma unroll
            for (int nh = 0; nh < 2; ++nh)
#pragma unroll
                for (int nj = 0; nj < 2; ++nj) acc[mh][mi][nh][nj] = z;

    // prologue: stage kt0 into d=0
    gload16(aS[0][0], (u16*)As + 0 * 8192 + 0 * 4096 + wv * 512);
    gload16(aS[0][1], (u16*)As + 0 * 8192 + 1 * 4096 + wv * 512);
    gload16(bS[0],    (u16*)Bs + 0 * 4096 + wv * 512);
    gload16(bS[1],    (u16*)Bs + 1 * 4096 + wv * 512);
    gload16(aS[1][0], (u16*)As + 1 * 8192 + 0 * 4096 + wv * 512);
    gload16(aS[1][1], (u16*)As + 1 * 8192 + 1 * 4096 + wv * 512);
    WVM(0);
    BAR();

    bf16x8 aF[2][2], bF0[2][2], bF1[2][2];

    for (int kt = 0; kt < NKT; ++kt) {
        const int d = kt & 1, d2 = d ^ 1;
        const int dA = d * 32768, dB = d * 16384;
        const int kno = (kt + 1) * BK;
        const bool st = (kt + 1 < NKT);

        // phase 0: (mh0, nh0)
        if (st) {
            gload16(aS[0][0] + kno, (u16*)As + (d2 * 2 + 0) * 8192 + 0 * 4096 + wv * 512);
            gload16(aS[0][1] + kno, (u16*)As + (d2 * 2 + 0) * 8192 + 1 * 4096 + wv * 512);
            WVM(5);
        } else { WVM(3); }
        BAR();
#pragma unroll
        for (int mi = 0; mi < 2; ++mi)
#pragma unroll
            for (int kk = 0; kk < 2; ++kk)
                aF[mi][kk] = *(const bf16x8*)(AbC + dA + 0 * 16384 + aro[mi] + swz[kk]);
#pragma unroll
        for (int nj = 0; nj < 2; ++nj)
#pragma unroll
            for (int kk = 0; kk < 2; ++kk)
                bF0[nj][kk] = *(const bf16x8*)(BbC + dB + 0 * 8192 + bro[nj] + swz[kk]);
        __builtin_amdgcn_s_setprio(1);
#pragma unroll
        for (int mi = 0; mi < 2; ++mi)
#pragma unroll
            for (int nj = 0; nj < 2; ++nj)
#pragma unroll
                for (int kk = 0; kk < 2; ++kk)
                    acc[0][mi][0][nj] = __builtin_amdgcn_mfma_f32_16x16x32_bf16(aF[mi][kk], bF0[nj][kk], acc[0][mi][0][nj], 0, 0, 0);
        __builtin_amdgcn_s_setprio(0);
        BAR();

        // phase 1: (mh0, nh1)
        if (st) { gload16(bS[0] + kno, (u16*)Bs + (d2 * 2 + 0) * 4096 + wv * 512); WVM(5); }
        else    { WVM(2); }
        BAR();
#pragma unroll
        for (int nj = 0; nj < 2; ++nj)
#pragma unroll
            for (int kk = 0; kk < 2; ++kk)
                bF1[nj][kk] = *(const bf16x8*)(BbC + dB + 1 * 8192 + bro[nj] + swz[kk]);
        __builtin_amdgcn_s_setprio(1);
#pragma unroll
        for (int mi = 0; mi < 2; ++mi)
#pragma unroll
            for (int nj = 0; nj < 2; ++nj)
#pragma unroll
                for (int kk = 0; kk < 2; ++kk)
                    acc[0][mi][1][nj] = __builtin_amdgcn_mfma_f32_16x16x32_bf16(aF[mi][kk], bF1[nj][kk], acc[0][mi][1][nj], 0, 0, 0);
        __builtin_amdgcn_s_setprio(0);
        BAR();

        // phase 2: (mh1, nh0)
        if (st) { gload16(bS[1] + kno, (u16*)Bs + (d2 * 2 + 1) * 4096 + wv * 512); WVM(4); }
        else    { WVM(0); }
        BAR();
#pragma unroll
        for (int mi = 0; mi < 2; ++mi)
#pragma unroll
            for (int kk = 0; kk < 2; ++kk)
                aF[mi][kk] = *(const bf16x8*)(AbC + dA + 1 * 16384 + aro[mi] + swz[kk]);
        __builtin_amdgcn_s_setprio(1);
#pragma unroll
        for (int mi = 0; mi < 2; ++mi)
#pragma unroll
            for (int nj = 0; nj < 2; ++nj)
#pragma unroll
                for (int kk = 0; kk < 2; ++kk)
                    acc[1][mi][0][nj] = __builtin_amdgcn_mfma_f32_16x16x32_bf16(aF[mi][kk], bF0[nj][kk], acc[1][mi][0][nj], 0, 0, 0);
        __builtin_amdgcn_s_setprio(0);
        BAR();

        // phase 3: (mh1, nh1)
        if (st) {
            gload16(aS[1][0] + kno, (u16*)As + (d2 * 2 + 1) * 8192 + 0 * 4096 + wv * 512);
            gload16(aS[1][1] + kno, (u16*)As + (d2 * 2 + 1) * 8192 + 1 * 4096 + wv * 512);
        }
        BAR();
        __builtin_amdgcn_s_setprio(1);
#pragma unroll
        for (int mi = 0; mi < 2; ++mi)
#pragma unroll
            for (int nj = 0; nj < 2; ++nj)
#pragma unroll
                for (int kk = 0; kk < 2; ++kk)
                    acc[1][mi][1][nj] = __builtin_amdgcn_mfma_f32_16x16x32_bf16(aF[mi][kk], bF1[nj][kk], acc[1][mi][1][nj], 0, 0, 0);
        __builtin_amdgcn_s_setprio(0);
        BAR();
    }

    // epilogue: store raw down-proj results (bf16); combine applies w + bias
#pragma unroll
    for (int mh = 0; mh < 2; ++mh)
#pragma unroll
        for (int mi = 0; mi < 2; ++mi)
#pragma unroll
            for (int nh = 0; nh < 2; ++nh)
#pragma unroll
                for (int nj = 0; nj < 2; ++nj) {
                    const int col = n0 + nh * 64 + (wv >> 2) * 32 + nj * 16 + lcol;
#pragma unroll
                    for (int rg = 0; rg < 4; ++rg) {
                        const int row = mh * 128 + (wv & 3) * 32 + mi * 16 + lk * 4 + rg;
                        if (r0 + row < cs)
                            down[(size_t)(rbase + r0 + row) * H_DIM + col] = f2bf(acc[mh][mi][nh][nj][rg]);
                    }
                }
}

// ---------------------------------------------------------------------------
// Combine: out[t][h] = w0*(down[row0][h]+b2[e0][h]) + w1*(down[row1][h]+b2[e1][h])
// ---------------------------------------------------------------------------
__global__ __launch_bounds__(256) void k_combine(
    const int* __restrict__ tope, const float2* __restrict__ topw,
    const int2* __restrict__ pos, const int* __restrict__ rowb,
    const float* __restrict__ b2, const u16* __restrict__ down,
    float* __restrict__ out) {
    const int t = blockIdx.x;
    const int c = threadIdx.x * 4;
    const int pk = tope[t];
    const int e0 = pk & 0xff, e1 = pk >> 8;
    const int2 pp = pos[t];
    const float2 w = topw[t];
    const size_t ro0 = (size_t)(rowb[e0] + pp.x) * H_DIM;
    const size_t ro1 = (size_t)(rowb[e1] + pp.y) * H_DIM;
    ushort4 d0 = *(const ushort4*)(down + ro0 + c);
    ushort4 d1 = *(const ushort4*)(down + ro1 + c);
    float4 bb0 = *(const float4*)(b2 + e0 * H_DIM + c);
    float4 bb1 = *(const float4*)(b2 + e1 * H_DIM + c);
    float4 o;
    o.x = w.x * (bf2f(d0.x) + bb0.x) + w.y * (bf2f(d1.x) + bb1.x);
    o.y = w.x * (bf2f(d0.y) + bb0.y) + w.y * (bf2f(d1.y) + bb1.y);
    o.z = w.x * (bf2f(d0.z) + bb0.z) + w.y * (bf2f(d1.z) + bb1.z);
    o.w = w.x * (bf2f(d0.w) + bb0.w) + w.y * (bf2f(d1.w) + bb1.w);
    *(float4*)(out + (size_t)t * H_DIM + c) = o;
}

// ---------------------------------------------------------------------------
extern "C" void kernel_launch(void* const* d_in, const int* in_sizes, int n_in,
                              void* d_out, int out_size, void* d_ws, size_t ws_size,
                              hipStream_t stream) {
    const float* x   = (const float*)d_in[0];
    const float* rw  = (const float*)d_in[1];
    const float* w1  = (const float*)d_in[2];
    const float* b1  = (const float*)d_in[3];
    const float* w2  = (const float*)d_in[4];
    const float* b2  = (const float*)d_in[5];
    float* out = (float*)d_out;
    char* ws = (char*)d_ws;

    if (ws_size < WS_NEED) return;

    u16*    W1T  = (u16*)(ws + WS_W1T);
    u16*    DOWN = (u16*)(ws + WS_DOWN);   // aliases W1T (safe: used after gemm1)
    u16*    W2T  = (u16*)(ws + WS_W2T);
    u16*    ACT  = (u16*)(ws + WS_ACT);
    int*    ETOK = (int*)(ws + WS_ETOK);
    int2*   POS  = (int2*)(ws + WS_POS);
    int*    CNT  = (int*)(ws + WS_CNT);
    int*    ROWB = (int*)(ws + WS_ROWB);
    int*    ASG1 = (int*)(ws + WS_ASG1);
    int*    ASG2 = (int*)(ws + WS_ASG2);
    int*    TOPE = (int*)(ws + WS_TOPE);
    float2* TOPW = (float2*)(ws + WS_TOPW);
    u16*    XBF  = (u16*)(ws + WS_XBF);

    hipMemsetAsync(CNT, 0, E_NUM * sizeof(int), stream);

    k_xbf<<<T_TOK * H_DIM / 2048, 256, 0, stream>>>(x, XBF);
    k_transpose_w1<<<dim3(32, 16, 8), 256, 0, stream>>>(w1, W1T);
    k_transpose_w2<<<dim3(16, 16, 8), 256, 0, stream>>>(w2, W2T);
    k_router_top2<<<T_TOK / 4, 256, 0, stream>>>(x, rw, TOPE, TOPW);
    k_router_scatter<<<T_TOK / 256, 256, 0, stream>>>(TOPE, CNT, ETOK, POS);
    k_schedule<<<1, 64, 0, stream>>>(CNT, ROWB, ASG1, ASG2);
    k_gemm1<<<dim3(8, MAXT1), 512, 0, stream>>>(XBF, W1T, b1, ETOK, CNT, ROWB, ASG1, ACT);
    k_gemm2<<<dim3(8, MAXT2), 512, 0, stream>>>(ACT, W2T, CNT, ROWB, ASG2, DOWN);
    k_combine<<<T_TOK, 256, 0, stream>>>(TOPE, TOPW, POS, ROWB, b2, DOWN, out);
}

// Round 9
// 165.214 us; speedup vs baseline: 1.1965x; 1.1965x over previous
//
#include <hip/hip_runtime.h>
#include <hip/hip_bf16.h>
#include <cstdint>
#include <cstddef>

// Problem constants
constexpr int T_TOK = 4096;   // B*S
constexpr int H_DIM = 1024;
constexpr int E_NUM = 8;
constexpr int I_DIM = 1024;
constexpr int F2    = 2048;   // 2*I
constexpr float ALPHA = 1.702f;
constexpr float LIMIT = 7.0f;
constexpr int BM = 128;       // GEMM row tile
constexpr int BK = 32;        // GEMM k tile
constexpr int NT = 32;        // k-steps (K=1024)
constexpr int MAXT = 72;      // >= sum(ceil(cnt_e/128)) worst case (71)

using u16    = unsigned short;
using bf16x8 = __attribute__((ext_vector_type(8))) __bf16;
using s16x8  = __attribute__((ext_vector_type(8))) short;
using f32x4  = __attribute__((ext_vector_type(4))) float;

// Workspace layout (bytes). DOWN aliases W1T (gemm1 finishes with W1T before
// gemm2 writes DOWN; transposes rewrite W1T every call — deterministic).
constexpr size_t WS_W1T  = 0;                        // [E][2][I][H] bf16
constexpr size_t WS_DOWN = 0;                        // [8192][H] bf16 (alias)
constexpr size_t WS_W2T  = 33554432;                 // [E][H][I] bf16
constexpr size_t WS_ACT  = 50331648;                 // [8192][I] bf16
constexpr size_t WS_ETOK = 67108864;                 // [E][T] int
constexpr size_t WS_POS  = 67239936;                 // [T] int2
constexpr size_t WS_CNT  = 67272704;                 // [E] int
constexpr size_t WS_ROWB = 67272736;                 // [E] int
constexpr size_t WS_ASGN = 67272768;                 // [MAXT] int (1KB reserved)
constexpr size_t WS_TOPE = 67273792;                 // [T] int
constexpr size_t WS_TOPW = 67290176;                 // [T] float2
constexpr size_t WS_XBF  = 67322944;                 // [T][H] bf16
constexpr size_t WS_NEED = 75711552;

__device__ __forceinline__ u16 f2bf(float f) {
    union { float f; unsigned u; } v; v.f = f;
    return (u16)((v.u + 0x7FFFu + ((v.u >> 16) & 1u)) >> 16);   // RNE
}
__device__ __forceinline__ float bf2f(u16 u) {
    union { unsigned u; float f; } v; v.u = (unsigned)u << 16; return v.f;
}

__device__ __forceinline__ s16x8 pack8(float4 a, float4 b) {
    s16x8 r;
    r[0] = (short)f2bf(a.x); r[1] = (short)f2bf(a.y);
    r[2] = (short)f2bf(a.z); r[3] = (short)f2bf(a.w);
    r[4] = (short)f2bf(b.x); r[5] = (short)f2bf(b.y);
    r[6] = (short)f2bf(b.z); r[7] = (short)f2bf(b.w);
    return r;
}

// async global -> LDS, 16B per lane. LDS dest = wave-uniform base + lane*16.
__device__ __forceinline__ void gload16(const void* g, void* l) {
    __builtin_amdgcn_global_load_lds((const __attribute__((address_space(1))) unsigned*)g,
                                     (__attribute__((address_space(3))) unsigned*)l,
                                     16, 0, 0);
}

// drain own stage loads + ds ops, then raw barrier (R5-proven single barrier).
__device__ __forceinline__ void pipe_sync() {
    __builtin_amdgcn_sched_barrier(0);
    asm volatile("s_waitcnt vmcnt(0) lgkmcnt(0)" ::: "memory");
    __builtin_amdgcn_s_barrier();
    __builtin_amdgcn_sched_barrier(0);
}

// ---------------------------------------------------------------------------
// x fp32 -> bf16 (once)
// ---------------------------------------------------------------------------
__global__ __launch_bounds__(256) void k_xbf(const float* __restrict__ x,
                                             u16* __restrict__ xbf) {
    const size_t i = ((size_t)blockIdx.x * 256 + threadIdx.x) * 8;
    float4 a = *(const float4*)(x + i);
    float4 b = *(const float4*)(x + i + 4);
    *(s16x8*)(xbf + i) = pack8(a, b);
}

// ---------------------------------------------------------------------------
// Transpose gate_up_proj [E][H][2I] fp32 -> [E][2][I][H] bf16 (de-interleave)
// ---------------------------------------------------------------------------
__global__ __launch_bounds__(256) void k_transpose_w1(const float* __restrict__ in,
                                                      u16* __restrict__ out) {
    __shared__ float tile[64][65];
    const int e = blockIdx.z, c0 = blockIdx.x * 64, h0 = blockIdx.y * 64;
    const int tid = threadIdx.x;
    const float* src = in + ((size_t)e * H_DIM + h0) * F2 + c0;
#pragma unroll
    for (int i = 0; i < 4; ++i) {
        int r = (tid >> 4) + i * 16, c = (tid & 15) * 4;
        float4 v = *(const float4*)(src + (size_t)r * F2 + c);
        tile[r][c] = v.x; tile[r][c + 1] = v.y; tile[r][c + 2] = v.z; tile[r][c + 3] = v.w;
    }
    __syncthreads();
    const int c = tid >> 2, hseg = (tid & 3) * 16;
    const int g = c & 1;
    const int f = (c0 + c) >> 1;
    u16* dst = out + (((size_t)e * 2 + g) * I_DIM + f) * H_DIM + h0 + hseg;
    s16x8 o0, o1;
#pragma unroll
    for (int j = 0; j < 8; ++j) o0[j] = (short)f2bf(tile[hseg + j][c]);
#pragma unroll
    for (int j = 0; j < 8; ++j) o1[j] = (short)f2bf(tile[hseg + 8 + j][c]);
    *(s16x8*)dst = o0;
    *(s16x8*)(dst + 8) = o1;
}

// ---------------------------------------------------------------------------
// Transpose down_proj [E][I][H] fp32 -> [E][H][I] bf16
// ---------------------------------------------------------------------------
__global__ __launch_bounds__(256) void k_transpose_w2(const float* __restrict__ in,
                                                      u16* __restrict__ out) {
    __shared__ float tile[64][65];
    const int e = blockIdx.z, h0 = blockIdx.x * 64, i0 = blockIdx.y * 64;
    const int tid = threadIdx.x;
    const float* src = in + ((size_t)e * I_DIM + i0) * H_DIM + h0;
#pragma unroll
    for (int i = 0; i < 4; ++i) {
        int r = (tid >> 4) + i * 16, c = (tid & 15) * 4;
        float4 v = *(const float4*)(src + (size_t)r * H_DIM + c);
        tile[r][c] = v.x; tile[r][c + 1] = v.y; tile[r][c + 2] = v.z; tile[r][c + 3] = v.w;
    }
    __syncthreads();
    const int c = tid >> 2, iseg = (tid & 3) * 16;
    u16* dst = out + ((size_t)e * H_DIM + h0 + c) * I_DIM + i0 + iseg;
    s16x8 o0, o1;
#pragma unroll
    for (int j = 0; j < 8; ++j) o0[j] = (short)f2bf(tile[iseg + j][c]);
#pragma unroll
    for (int j = 0; j < 8; ++j) o1[j] = (short)f2bf(tile[iseg + 8 + j][c]);
    *(s16x8*)dst = o0;
    *(s16x8*)(dst + 8) = o1;
}

// ---------------------------------------------------------------------------
// Router phase 1: fp32 logits, top-2, softmax. One wave per token. No atomics.
// ---------------------------------------------------------------------------
__global__ __launch_bounds__(256) void k_router_top2(const float* __restrict__ x,
                                                     const float* __restrict__ rw,
                                                     int* __restrict__ tope,
                                                     float2* __restrict__ topw) {
    const int wave = threadIdx.x >> 6, lane = threadIdx.x & 63;
    const int t = blockIdx.x * 4 + wave;
    const float* xr = x + (size_t)t * H_DIM;
    float acc[E_NUM];
#pragma unroll
    for (int e = 0; e < E_NUM; ++e) acc[e] = 0.f;
    for (int h = lane; h < H_DIM; h += 64) {
        float xv = xr[h];
        const float* r = rw + h * E_NUM;
#pragma unroll
        for (int e = 0; e < E_NUM; ++e) acc[e] += xv * r[e];
    }
#pragma unroll
    for (int e = 0; e < E_NUM; ++e) {
        float v = acc[e];
#pragma unroll
        for (int o = 32; o > 0; o >>= 1) v += __shfl_down(v, o);
        acc[e] = v;
    }
    if (lane == 0) {
        int e0 = 0; float v0 = acc[0];
#pragma unroll
        for (int e = 1; e < E_NUM; ++e) if (acc[e] > v0) { v0 = acc[e]; e0 = e; }
        int e1 = -1; float v1 = -3.4e38f;
#pragma unroll
        for (int e = 0; e < E_NUM; ++e) if (e != e0 && acc[e] > v1) { v1 = acc[e]; e1 = e; }
        float ew = expf(v1 - v0);
        float inv = 1.f / (1.f + ew);
        tope[t] = e0 | (e1 << 8);
        topw[t] = make_float2(inv, ew * inv);
    }
}

// ---------------------------------------------------------------------------
// Router phase 2: block-aggregated scatter (1 global atomic per expert/block).
// ---------------------------------------------------------------------------
__global__ __launch_bounds__(256) void k_router_scatter(const int* __restrict__ tope,
                                                        int* __restrict__ cnt,
                                                        int* __restrict__ ent_tok,
                                                        int2* __restrict__ pos) {
    __shared__ int lcnt[E_NUM];
    __shared__ int gbase[E_NUM];
    const int tid = threadIdx.x;
    const int t = blockIdx.x * 256 + tid;
    if (tid < E_NUM) lcnt[tid] = 0;
    __syncthreads();
    const int pk = tope[t];
    const int e0 = pk & 0xff, e1 = pk >> 8;
    const int o0 = atomicAdd(&lcnt[e0], 1);
    const int o1 = atomicAdd(&lcnt[e1], 1);
    __syncthreads();
    if (tid < E_NUM) gbase[tid] = atomicAdd(&cnt[tid], lcnt[tid]);
    __syncthreads();
    const int p0 = gbase[e0] + o0;
    const int p1 = gbase[e1] + o1;
    ent_tok[e0 * T_TOK + p0] = t;
    ent_tok[e1 * T_TOK + p1] = t;
    pos[t] = make_int2(p0, p1);
}

// ---------------------------------------------------------------------------
// Schedule: counts -> row bases + tile assignment table (BM=128 tiles).
// ---------------------------------------------------------------------------
__global__ void k_schedule(const int* __restrict__ cnt, int* __restrict__ rowbase,
                           int* __restrict__ assign) {
    if (threadIdx.x == 0) {
        int rb = 0, na = 0;
        for (int e = 0; e < E_NUM; ++e) {
            rowbase[e] = rb;
            int nt = (cnt[e] + BM - 1) >> 7;
            for (int m = 0; m < nt; ++m) assign[na++] = (e << 16) | m;
            rb += cnt[e];
        }
        for (; na < MAXT; ++na) assign[na] = -1;
    }
}

// ---------------------------------------------------------------------------
// GEMM1: 128 entries x 64 act-cols (B-tile: [gate64 | up64] rows), BK=32.
// 256 thr / 4 waves (2Mx2N). Double-buffered 32KB LDS, 4 blocks/CU (16
// waves/CU). Swizzle: slot ^= (row>>1)&3 — spreads 16 consecutive rows over
// all 8 bank-quads (2-way aliasing only = free).
// ---------------------------------------------------------------------------
__global__ __launch_bounds__(256, 4) void k_gemm1(
    const u16* __restrict__ xbf, const u16* __restrict__ w1t,
    const float* __restrict__ bias, const int* __restrict__ ent_tok,
    const int* __restrict__ cnt, const int* __restrict__ rowbase,
    const int* __restrict__ assign, u16* __restrict__ act) {
    const int a = assign[blockIdx.y];
    if (a < 0) return;
    const int e = a >> 16, mt = a & 0xffff;
    const int j0 = blockIdx.x * 64;           // act-col base
    const int cs = cnt[e], r0 = mt * BM;
    __shared__ __align__(16) u16 As[2][BM * BK];   // 2 x 8KB
    __shared__ __align__(16) u16 Bs[2][BM * BK];   // 2 x 8KB
    const int tid = threadIdx.x, lane = tid & 63, wv = tid >> 6;
    const int lr = lane >> 2;                       // row-in-16 (0..15)
    const int sm = (lane & 3) ^ ((lr >> 1) & 3);    // inverse-swizzled src slot
    // staging: per thread 2 A-instr + 2 B-instr; instr j covers 16 rows
    const u16* asrc[2]; const u16* bsrc[2]; int dofs[2];
#pragma unroll
    for (int j = 0; j < 2; ++j) {
        const int row = wv * 32 + j * 16 + lr;
        const int aent = r0 + row;
        const int tok = (aent < cs) ? ent_tok[e * T_TOK + aent] : 0;
        asrc[j] = xbf + (size_t)tok * H_DIM + sm * 8;
        const int g = row >> 6;                     // 0: gate rows, 1: up rows
        const int f = j0 + (row & 63);
        bsrc[j] = w1t + (((size_t)e * 2 + g) * I_DIM + f) * H_DIM + sm * 8;
        dofs[j] = (wv * 32 + j * 16) * BK;
    }
    // compute-side byte offsets (loop-invariant)
    const int wm = wv >> 1, wn = wv & 1;
    const int lcol = lane & 15, lk = lane >> 4;
    int aoff[4], goff[2], uoff[2];
#pragma unroll
    for (int mi = 0; mi < 4; ++mi) {
        const int r = wm * 64 + mi * 16 + lcol;
        aoff[mi] = r * 64 + ((lk ^ ((r >> 1) & 3)) << 4);
    }
#pragma unroll
    for (int nj = 0; nj < 2; ++nj) {
        const int rg_ = wn * 32 + nj * 16 + lcol;
        const int ru  = 64 + rg_;
        goff[nj] = rg_ * 64 + ((lk ^ ((rg_ >> 1) & 3)) << 4);
        uoff[nj] = ru  * 64 + ((lk ^ ((ru  >> 1) & 3)) << 4);
    }
    f32x4 ag[4][2], au[4][2];
    const f32x4 z = {0.f, 0.f, 0.f, 0.f};
#pragma unroll
    for (int mi = 0; mi < 4; ++mi) { ag[mi][0] = z; ag[mi][1] = z; au[mi][0] = z; au[mi][1] = z; }
    // prologue: stage k-tile 0
#pragma unroll
    for (int j = 0; j < 2; ++j) {
        gload16(asrc[j], &As[0][dofs[j]]);
        gload16(bsrc[j], &Bs[0][dofs[j]]);
    }
    pipe_sync();
    int cur = 0;
    for (int t = 0; t < NT; ++t) {
        if (t + 1 < NT) {                      // issue next-tile stage FIRST
            const int kn = (t + 1) * BK;
            u16* Ad = As[cur ^ 1]; u16* Bd = Bs[cur ^ 1];
#pragma unroll
            for (int j = 0; j < 2; ++j) {
                gload16(asrc[j] + kn, Ad + dofs[j]);
                gload16(bsrc[j] + kn, Bd + dofs[j]);
            }
        }
        const char* Ab = (const char*)As[cur];
        const char* Bb = (const char*)Bs[cur];
        bf16x8 af[4];
#pragma unroll
        for (int mi = 0; mi < 4; ++mi) af[mi] = *(const bf16x8*)(Ab + aoff[mi]);
        const bf16x8 g0 = *(const bf16x8*)(Bb + goff[0]);
        const bf16x8 g1 = *(const bf16x8*)(Bb + goff[1]);
        const bf16x8 u0 = *(const bf16x8*)(Bb + uoff[0]);
        const bf16x8 u1 = *(const bf16x8*)(Bb + uoff[1]);
#pragma unroll
        for (int mi = 0; mi < 4; ++mi) {
            ag[mi][0] = __builtin_amdgcn_mfma_f32_16x16x32_bf16(af[mi], g0, ag[mi][0], 0, 0, 0);
            au[mi][0] = __builtin_amdgcn_mfma_f32_16x16x32_bf16(af[mi], u0, au[mi][0], 0, 0, 0);
            ag[mi][1] = __builtin_amdgcn_mfma_f32_16x16x32_bf16(af[mi], g1, ag[mi][1], 0, 0, 0);
            au[mi][1] = __builtin_amdgcn_mfma_f32_16x16x32_bf16(af[mi], u1, au[mi][1], 0, 0, 0);
        }
        pipe_sync();                           // next-tile stage drained (hidden under compute)
        cur ^= 1;
    }
    // epilogue: clamp + GLU, store bf16 act
    const int rbase = rowbase[e];
#pragma unroll
    for (int mi = 0; mi < 4; ++mi) {
#pragma unroll
        for (int nj = 0; nj < 2; ++nj) {
            const int col = j0 + wn * 32 + nj * 16 + lcol;
            const float bg_ = bias[e * F2 + 2 * col];
            const float bu_ = bias[e * F2 + 2 * col + 1];
#pragma unroll
            for (int rg = 0; rg < 4; ++rg) {
                const int r = wm * 64 + mi * 16 + lk * 4 + rg;
                if (r0 + r < cs) {
                    float gv = ag[mi][nj][rg] + bg_;
                    float uv = au[mi][nj][rg] + bu_;
                    gv = fminf(gv, LIMIT);
                    uv = fminf(fmaxf(uv, -LIMIT), LIMIT);
                    const float glu = gv / (1.f + expf(-ALPHA * gv));
                    act[(size_t)(rbase + r0 + r) * I_DIM + col] = f2bf((uv + 1.f) * glu);
                }
            }
        }
    }
}

// ---------------------------------------------------------------------------
// GEMM2: 128 entries x 128 out-cols, BK=32, same structure; writes raw DOWN
// (no atomics; combine applies routing weight + bias).
// ---------------------------------------------------------------------------
__global__ __launch_bounds__(256, 4) void k_gemm2(
    const u16* __restrict__ act, const u16* __restrict__ w2t,
    const int* __restrict__ cnt, const int* __restrict__ rowbase,
    const int* __restrict__ assign, u16* __restrict__ down) {
    const int a = assign[blockIdx.y];
    if (a < 0) return;
    const int e = a >> 16, mt = a & 0xffff;
    const int n0 = blockIdx.x * 128;
    const int cs = cnt[e], r0 = mt * BM, rbase = rowbase[e];
    __shared__ __align__(16) u16 As[2][BM * BK];
    __shared__ __align__(16) u16 Bs[2][BM * BK];
    const int tid = threadIdx.x, lane = tid & 63, wv = tid >> 6;
    const int lr = lane >> 2;
    const int sm = (lane & 3) ^ ((lr >> 1) & 3);
    const u16* asrc[2]; const u16* bsrc[2]; int dofs[2];
#pragma unroll
    for (int j = 0; j < 2; ++j) {
        const int row = wv * 32 + j * 16 + lr;
        int ar = rbase + r0 + row;
        if (ar > 2 * T_TOK - 1) ar = 2 * T_TOK - 1;
        asrc[j] = act + (size_t)ar * I_DIM + sm * 8;
        bsrc[j] = w2t + ((size_t)e * H_DIM + n0 + row) * I_DIM + sm * 8;
        dofs[j] = (wv * 32 + j * 16) * BK;
    }
    const int wm = wv >> 1, wn = wv & 1;
    const int lcol = lane & 15, lk = lane >> 4;
    int aoff[4], boff[4];
#pragma unroll
    for (int mi = 0; mi < 4; ++mi) {
        const int r = wm * 64 + mi * 16 + lcol;
        const int b = wn * 64 + mi * 16 + lcol;
        aoff[mi] = r * 64 + ((lk ^ ((r >> 1) & 3)) << 4);
        boff[mi] = b * 64 + ((lk ^ ((b >> 1) & 3)) << 4);
    }
    f32x4 acc[4][4];
    const f32x4 z = {0.f, 0.f, 0.f, 0.f};
#pragma unroll
    for (int mi = 0; mi < 4; ++mi)
#pragma unroll
        for (int nj = 0; nj < 4; ++nj) acc[mi][nj] = z;
#pragma unroll
    for (int j = 0; j < 2; ++j) {
        gload16(asrc[j], &As[0][dofs[j]]);
        gload16(bsrc[j], &Bs[0][dofs[j]]);
    }
    pipe_sync();
    int cur = 0;
    for (int t = 0; t < NT; ++t) {
        if (t + 1 < NT) {
            const int kn = (t + 1) * BK;
            u16* Ad = As[cur ^ 1]; u16* Bd = Bs[cur ^ 1];
#pragma unroll
            for (int j = 0; j < 2; ++j) {
                gload16(asrc[j] + kn, Ad + dofs[j]);
                gload16(bsrc[j] + kn, Bd + dofs[j]);
            }
        }
        const char* Ab = (const char*)As[cur];
        const char* Bb = (const char*)Bs[cur];
        bf16x8 af[4], bf_[4];
#pragma unroll
        for (int mi = 0; mi < 4; ++mi) af[mi]  = *(const bf16x8*)(Ab + aoff[mi]);
#pragma unroll
        for (int nj = 0; nj < 4; ++nj) bf_[nj] = *(const bf16x8*)(Bb + boff[nj]);
#pragma unroll
        for (int mi = 0; mi < 4; ++mi)
#pragma unroll
            for (int nj = 0; nj < 4; ++nj)
                acc[mi][nj] = __builtin_amdgcn_mfma_f32_16x16x32_bf16(af[mi], bf_[nj], acc[mi][nj], 0, 0, 0);
        pipe_sync();
        cur ^= 1;
    }
#pragma unroll
    for (int mi = 0; mi < 4; ++mi) {
#pragma unroll
        for (int nj = 0; nj < 4; ++nj) {
            const int col = n0 + wn * 64 + nj * 16 + lcol;
#pragma unroll
            for (int rg = 0; rg < 4; ++rg) {
                const int r = wm * 64 + mi * 16 + lk * 4 + rg;
                if (r0 + r < cs)
                    down[(size_t)(rbase + r0 + r) * H_DIM + col] = f2bf(acc[mi][nj][rg]);
            }
        }
    }
}

// ---------------------------------------------------------------------------
// Combine: out[t][h] = w0*(down[row0][h]+b2[e0][h]) + w1*(down[row1][h]+b2[e1][h])
// ---------------------------------------------------------------------------
__global__ __launch_bounds__(256) void k_combine(
    const int* __restrict__ tope, const float2* __restrict__ topw,
    const int2* __restrict__ pos, const int* __restrict__ rowb,
    const float* __restrict__ b2, const u16* __restrict__ down,
    float* __restrict__ out) {
    const int t = blockIdx.x;
    const int c = threadIdx.x * 4;
    const int pk = tope[t];
    const int e0 = pk & 0xff, e1 = pk >> 8;
    const int2 pp = pos[t];
    const float2 w = topw[t];
    const size_t ro0 = (size_t)(rowb[e0] + pp.x) * H_DIM;
    const size_t ro1 = (size_t)(rowb[e1] + pp.y) * H_DIM;
    ushort4 d0 = *(const ushort4*)(down + ro0 + c);
    ushort4 d1 = *(const ushort4*)(down + ro1 + c);
    float4 bb0 = *(const float4*)(b2 + e0 * H_DIM + c);
    float4 bb1 = *(const float4*)(b2 + e1 * H_DIM + c);
    float4 o;
    o.x = w.x * (bf2f(d0.x) + bb0.x) + w.y * (bf2f(d1.x) + bb1.x);
    o.y = w.x * (bf2f(d0.y) + bb0.y) + w.y * (bf2f(d1.y) + bb1.y);
    o.z = w.x * (bf2f(d0.z) + bb0.z) + w.y * (bf2f(d1.z) + bb1.z);
    o.w = w.x * (bf2f(d0.w) + bb0.w) + w.y * (bf2f(d1.w) + bb1.w);
    *(float4*)(out + (size_t)t * H_DIM + c) = o;
}

// ---------------------------------------------------------------------------
extern "C" void kernel_launch(void* const* d_in, const int* in_sizes, int n_in,
                              void* d_out, int out_size, void* d_ws, size_t ws_size,
                              hipStream_t stream) {
    const float* x   = (const float*)d_in[0];
    const float* rw  = (const float*)d_in[1];
    const float* w1  = (const float*)d_in[2];
    const float* b1  = (const float*)d_in[3];
    const float* w2  = (const float*)d_in[4];
    const float* b2  = (const float*)d_in[5];
    float* out = (float*)d_out;
    char* ws = (char*)d_ws;

    if (ws_size < WS_NEED) return;

    u16*    W1T  = (u16*)(ws + WS_W1T);
    u16*    DOWN = (u16*)(ws + WS_DOWN);   // aliases W1T (safe: used after gemm1)
    u16*    W2T  = (u16*)(ws + WS_W2T);
    u16*    ACT  = (u16*)(ws + WS_ACT);
    int*    ETOK = (int*)(ws + WS_ETOK);
    int2*   POS  = (int2*)(ws + WS_POS);
    int*    CNT  = (int*)(ws + WS_CNT);
    int*    ROWB = (int*)(ws + WS_ROWB);
    int*    ASGN = (int*)(ws + WS_ASGN);
    int*    TOPE = (int*)(ws + WS_TOPE);
    float2* TOPW = (float2*)(ws + WS_TOPW);
    u16*    XBF  = (u16*)(ws + WS_XBF);

    hipMemsetAsync(CNT, 0, E_NUM * sizeof(int), stream);

    k_xbf<<<T_TOK * H_DIM / 2048, 256, 0, stream>>>(x, XBF);
    k_transpose_w1<<<dim3(32, 16, 8), 256, 0, stream>>>(w1, W1T);
    k_transpose_w2<<<dim3(16, 16, 8), 256, 0, stream>>>(w2, W2T);
    k_router_top2<<<T_TOK / 4, 256, 0, stream>>>(x, rw, TOPE, TOPW);
    k_router_scatter<<<T_TOK / 256, 256, 0, stream>>>(TOPE, CNT, ETOK, POS);
    k_schedule<<<1, 64, 0, stream>>>(CNT, ROWB, ASGN);
    k_gemm1<<<dim3(16, MAXT), 256, 0, stream>>>(XBF, W1T, b1, ETOK, CNT, ROWB, ASGN, ACT);
    k_gemm2<<<dim3(8, MAXT), 256, 0, stream>>>(ACT, W2T, CNT, ROWB, ASGN, DOWN);
    k_combine<<<T_TOK, 256, 0, stream>>>(TOPE, TOPW, POS, ROWB, b2, DOWN, out);
}